// Round 1
// baseline (827.085 us; speedup 1.0000x reference)
//
#include <hip/hip_runtime.h>
#include <math.h>

// Problem constants (fixed by setup_inputs)
constexpr int Bb = 128;   // batch
constexpr int Nn = 2048;  // input capsules
constexpr int Dd = 8;     // input capsule dim
constexpr int Jj = 32;    // output capsules
constexpr int Pp = 16;    // output capsule dim

// Tiling
constexpr int BT = 4;         // batches per wave register tile (W-reuse factor)
constexpr int WV = 4;         // waves per block
constexpr int BB = BT * WV;   // 16 batches per block
constexpr int BN = 32;        // n per block
constexpr int NBC = Bb / BB;  // 8 batch-chunks
constexpr int NNC = Nn / BN;  // 64 n-chunks
constexpr int GRID = NBC * NNC; // 512 blocks

// Routing pass kernel.
// PASS==0: c is uniform (softmax of zeros) -> S = sum_n u_hat  (1/J applied in squash)
// PASS>0 : logits = dot(OS[b,j,:], u_hat[b,j,n,:]); c = softmax_j; S += c*u_hat
// Lane mapping: j = lane>>1 (32 output capsules), p-half = lane&1 (8 of 16 p's).
template<int PASS>
__global__ __launch_bounds__(256, 2)
void route_k(const float* __restrict__ x, const float* __restrict__ W,
             const float* __restrict__ OS, float* __restrict__ S)
{
    const int tid  = threadIdx.x;
    const int wave = __builtin_amdgcn_readfirstlane(tid >> 6); // force SGPR
    const int lane = tid & 63;
    const int bc = blockIdx.x & (NBC - 1);
    const int nc = blockIdx.x >> 3;           // / NBC
    const int b0 = bc * BB + wave * BT;
    const int n0 = nc * BN;
    const int j  = lane >> 1;
    const int pb = (lane & 1) * 8;

    // Running output-sum fragment for logits (PASS>0)
    float osum[BT][8];
    if (PASS > 0) {
        #pragma unroll
        for (int bb = 0; bb < BT; ++bb) {
            const float4* op = reinterpret_cast<const float4*>(
                OS + (size_t)((b0 + bb) * Jj + j) * Pp + pb);
            float4 a = op[0], b4 = op[1];
            osum[bb][0] = a.x;  osum[bb][1] = a.y;  osum[bb][2] = a.z;  osum[bb][3] = a.w;
            osum[bb][4] = b4.x; osum[bb][5] = b4.y; osum[bb][6] = b4.z; osum[bb][7] = b4.w;
        }
    }

    float Sa[BT][8];
    #pragma unroll
    for (int bb = 0; bb < BT; ++bb)
        #pragma unroll
        for (int pp = 0; pp < 8; ++pp) Sa[bb][pp] = 0.f;

    for (int nn = 0; nn < BN; ++nn) {
        const int n = n0 + nn;

        // x[b,n,0:8] — wave-uniform addresses (broadcast / scalarizable)
        float xv[BT][8];
        #pragma unroll
        for (int bb = 0; bb < BT; ++bb) {
            const float4* xp = reinterpret_cast<const float4*>(
                x + (size_t)((b0 + bb) * Nn + n) * Dd);
            float4 a = xp[0], c4 = xp[1];
            xv[bb][0] = a.x;  xv[bb][1] = a.y;  xv[bb][2] = a.z;  xv[bb][3] = a.w;
            xv[bb][4] = c4.x; xv[bb][5] = c4.y; xv[bb][6] = c4.z; xv[bb][7] = c4.w;
        }

        // u_hat[j, pb+pp] for BT batches; W loaded once per pp, reused for 4 batches
        float uh[BT][8];
        #pragma unroll
        for (int pp = 0; pp < 8; ++pp) {
            const float4* wp = reinterpret_cast<const float4*>(
                W + ((size_t)(j * Nn + n) * Pp + pb + pp) * Dd);
            float4 a = wp[0], c4 = wp[1];
            float wv[8] = {a.x, a.y, a.z, a.w, c4.x, c4.y, c4.z, c4.w};
            #pragma unroll
            for (int bb = 0; bb < BT; ++bb) {
                float acc = 0.f;
                #pragma unroll
                for (int d = 0; d < 8; ++d) acc = fmaf(wv[d], xv[bb][d], acc);
                uh[bb][pp] = acc;
            }
        }

        if (PASS == 0) {
            #pragma unroll
            for (int bb = 0; bb < BT; ++bb)
                #pragma unroll
                for (int pp = 0; pp < 8; ++pp) Sa[bb][pp] += uh[bb][pp];
        } else {
            #pragma unroll
            for (int bb = 0; bb < BT; ++bb) {
                // logits[b,j,n] = dot(osum[b,j,:], u_hat[b,j,n,:])
                float lg = 0.f;
                #pragma unroll
                for (int pp = 0; pp < 8; ++pp)
                    lg = fmaf(osum[bb][pp], uh[bb][pp], lg);
                lg += __shfl_xor(lg, 1, 64);   // merge p-halves -> full dot over 16 p
                // softmax over j (32 distinct values, duplicated on lane pairs):
                // butterfly over bits 1..5 reduces each j exactly once
                float m = lg;
                #pragma unroll
                for (int mk = 2; mk <= 32; mk <<= 1)
                    m = fmaxf(m, __shfl_xor(m, mk, 64));
                float e = __expf(lg - m);
                float se = e;
                #pragma unroll
                for (int mk = 2; mk <= 32; mk <<= 1)
                    se += __shfl_xor(se, mk, 64);
                float c = e * __builtin_amdgcn_rcpf(se);
                #pragma unroll
                for (int pp = 0; pp < 8; ++pp)
                    Sa[bb][pp] = fmaf(c, uh[bb][pp], Sa[bb][pp]);
            }
        }
    }

    // Flush partial S (accumulated over this block's 32 n) — cross-n-chunk reduce
    #pragma unroll
    for (int bb = 0; bb < BT; ++bb) {
        float* sp = S + (size_t)((b0 + bb) * Jj + j) * Pp + pb;
        #pragma unroll
        for (int pp = 0; pp < 8; ++pp) atomicAdd(sp + pp, Sa[bb][pp]);
    }
}

// Squash S -> v = squash(scale*S); mode 0: OS = v; 1: OS += v; 2: out = v (final)
__global__ void squash_k(const float* __restrict__ S, float scale,
                         float* __restrict__ OS, float* __restrict__ out, int mode)
{
    int t = blockIdx.x * blockDim.x + threadIdx.x;
    if (t >= Bb * Jj) return;
    const float4* sp = reinterpret_cast<const float4*>(S + (size_t)t * Pp);
    float4 v0 = sp[0], v1 = sp[1], v2 = sp[2], v3 = sp[3];
    float v[16] = {v0.x, v0.y, v0.z, v0.w, v1.x, v1.y, v1.z, v1.w,
                   v2.x, v2.y, v2.z, v2.w, v3.x, v3.y, v3.z, v3.w};
    float s2 = 0.f;
    #pragma unroll
    for (int p = 0; p < 16; ++p) {
        float s = v[p] * scale;
        s2 += s * s;
    }
    // squash coefficient applied to s = scale*S:  s2/(1+s2)/sqrt(s2+eps)
    float g = s2 / ((1.f + s2) * sqrtf(s2 + 1e-7f)) * scale;
    if (mode == 0) {
        #pragma unroll
        for (int p = 0; p < 16; ++p) OS[(size_t)t * Pp + p] = g * v[p];
    } else if (mode == 1) {
        #pragma unroll
        for (int p = 0; p < 16; ++p) OS[(size_t)t * Pp + p] += g * v[p];
    } else {
        #pragma unroll
        for (int p = 0; p < 16; ++p) out[(size_t)t * Pp + p] = g * v[p];
    }
}

extern "C" void kernel_launch(void* const* d_in, const int* in_sizes, int n_in,
                              void* d_out, int out_size, void* d_ws, size_t ws_size,
                              hipStream_t stream)
{
    const float* x = (const float*)d_in[0];   // [128, 2048, 8]
    const float* W = (const float*)d_in[1];   // [32, 2048, 16, 8]
    float* out = (float*)d_out;               // [128, 32, 16]

    float* S  = (float*)d_ws;                 // 65536 floats (256 KB)
    float* OS = (float*)d_ws + (size_t)Bb * Jj * Pp; // 65536 floats

    const size_t Sbytes = (size_t)Bb * Jj * Pp * sizeof(float);
    dim3 rg(GRID), rb(256);
    dim3 sg((Bb * Jj + 255) / 256), sb(256);

    // Pass 0: uniform coupling
    hipMemsetAsync(S, 0, Sbytes, stream);
    route_k<0><<<rg, rb, 0, stream>>>(x, W, nullptr, S);
    squash_k<<<sg, sb, 0, stream>>>(S, 1.f / (float)Jj, OS, out, 0);

    // Pass 1
    hipMemsetAsync(S, 0, Sbytes, stream);
    route_k<1><<<rg, rb, 0, stream>>>(x, W, OS, S);
    squash_k<<<sg, sb, 0, stream>>>(S, 1.f, OS, out, 1);

    // Pass 2 (final)
    hipMemsetAsync(S, 0, Sbytes, stream);
    route_k<2><<<rg, rb, 0, stream>>>(x, W, OS, S);
    squash_k<<<sg, sb, 0, stream>>>(S, 1.f, OS, out, 2);
}

// Round 2
// 431.844 us; speedup vs baseline: 1.9152x; 1.9152x over previous
//
#include <hip/hip_runtime.h>
#include <math.h>

// Problem constants (fixed by setup_inputs)
constexpr int Bb = 128;   // batch
constexpr int Nn = 2048;  // input capsules
constexpr int Dd = 8;     // input capsule dim
constexpr int Jj = 32;    // output capsules
constexpr int Pp = 16;    // output capsule dim

// Tiling
constexpr int BT = 4;           // batches per wave register tile
constexpr int WV = 4;           // waves per block
constexpr int BB = BT * WV;     // 16 batches per block
constexpr int BN = 32;          // n per block
constexpr int NBC = Bb / BB;    // 8 batch-chunks
constexpr int NNC = Nn / BN;    // 64 n-chunks
constexpr int GRID = NBC * NNC; // 512 blocks
constexpr int SZ = Bb * Jj * Pp;        // 65536 floats (S / OS size)
constexpr int WSLICE_F4 = Jj * Pp * Dd / 4; // 1024 float4 per n-slice (16 KB)

// Routing pass kernel with LDS-staged, swizzle-laid-out W.
//
// LDS W layout: slice element chunk G (0..1023, global float4 order [j][p][dh])
// maps to (l = G>>4, k = G&15), stored at float4 slot  k*64 + ((l+k)&63).
// Read side: lane l = j*2+hp reads chunk k = pp*2+dh at the same formula.
// Both sides are the canonical conflict-free "base + 4*lane-ish" bank pattern.
template<int LOGITS, int ATOMIC>
__global__ __launch_bounds__(256, 2)
void route_k(const float* __restrict__ x, const float* __restrict__ W,
             const float* __restrict__ OS, float* __restrict__ S)
{
    __shared__ float4 wbuf[2][WSLICE_F4];   // 2 x 16 KB double buffer
    __shared__ float  xs[BB * BN * Dd];     // 16 KB x tile [b][n][d]

    const int tid  = threadIdx.x;
    const int wave = tid >> 6;
    const int lane = tid & 63;
    const int bc = blockIdx.x & (NBC - 1);
    const int nc = blockIdx.x >> 3;         // / NBC
    const int b0 = bc * BB;
    const int n0 = nc * BN;
    const int j  = lane >> 1;
    const int hp = lane & 1;                // which p-half

    // ---- stage x tile: x[b0..b0+16][n0..n0+32][0..8], coalesced ----
    {
        const int b  = tid >> 4;      // 0..15
        const int f0 = tid & 15;      // float4 lane within row
        const float4* src = reinterpret_cast<const float4*>(
            x + ((size_t)(b0 + b) * Nn + n0) * Dd);
        float4* dst = reinterpret_cast<float4*>(xs + (size_t)b * BN * Dd);
        #pragma unroll
        for (int i = 0; i < 4; ++i) dst[f0 + 16 * i] = src[f0 + 16 * i];
    }

    // ---- W staging (thread t handles chunks G = t + 256c, c=0..3) ----
    const float4* Wg = reinterpret_cast<const float4*>(W);
    const int tg = tid & 31;    // G & 31  (within-j f4 column p*2+dh)
    const int th = tid >> 5;    // G >> 5 base (j)
    const int kk = tid & 15;    // G & 15  -> k
    const int lb = tid >> 4;    // G >> 4 base -> l

    float4 st[4];
    auto load_slice = [&](int n) {
        const size_t base = (size_t)n * 32 + tg;
        #pragma unroll
        for (int c = 0; c < 4; ++c)
            st[c] = Wg[base + (size_t)(th + 8 * c) * (Nn * 32)];
    };
    auto store_slice = [&](int buf) {
        #pragma unroll
        for (int c = 0; c < 4; ++c)
            wbuf[buf][kk * 64 + ((lb + 16 * c + kk) & 63)] = st[c];
    };

    // Output-sum fragment for logits
    float osum[BT][8];
    if (LOGITS) {
        #pragma unroll
        for (int bb = 0; bb < BT; ++bb) {
            const float4* op = reinterpret_cast<const float4*>(
                OS + ((size_t)(b0 + wave * BT + bb) * Jj + j) * Pp + hp * 8);
            float4 a = op[0], b4 = op[1];
            osum[bb][0] = a.x;  osum[bb][1] = a.y;  osum[bb][2] = a.z;  osum[bb][3] = a.w;
            osum[bb][4] = b4.x; osum[bb][5] = b4.y; osum[bb][6] = b4.z; osum[bb][7] = b4.w;
        }
    }

    float Sa[BT][8];
    #pragma unroll
    for (int bb = 0; bb < BT; ++bb)
        #pragma unroll
        for (int pp = 0; pp < 8; ++pp) Sa[bb][pp] = 0.f;

    // Prologue: stage slice 0
    load_slice(n0);
    store_slice(0);
    __syncthreads();

    for (int nn = 0; nn < BN; ++nn) {
        if (nn + 1 < BN) load_slice(n0 + nn + 1);  // prefetch to regs early
        const int buf = nn & 1;

        // x values (LDS broadcast reads, wave-uniform addresses)
        float xv[BT][8];
        #pragma unroll
        for (int bb = 0; bb < BT; ++bb) {
            const float4* xp = reinterpret_cast<const float4*>(
                xs + ((size_t)(wave * BT + bb) * BN + nn) * Dd);
            float4 a = xp[0], c4 = xp[1];
            xv[bb][0] = a.x;  xv[bb][1] = a.y;  xv[bb][2] = a.z;  xv[bb][3] = a.w;
            xv[bb][4] = c4.x; xv[bb][5] = c4.y; xv[bb][6] = c4.z; xv[bb][7] = c4.w;
        }

        // u_hat from LDS W fragments (conflict-free swizzled reads)
        float uh[BT][8];
        #pragma unroll
        for (int pp = 0; pp < 8; ++pp) {
            const int k0 = 2 * pp, k1 = 2 * pp + 1;
            float4 a = wbuf[buf][k0 * 64 + ((lane + k0) & 63)];
            float4 b = wbuf[buf][k1 * 64 + ((lane + k1) & 63)];
            float wv[8] = {a.x, a.y, a.z, a.w, b.x, b.y, b.z, b.w};
            #pragma unroll
            for (int bb = 0; bb < BT; ++bb) {
                float acc = 0.f;
                #pragma unroll
                for (int d = 0; d < 8; ++d) acc = fmaf(wv[d], xv[bb][d], acc);
                uh[bb][pp] = acc;
            }
        }

        if (!LOGITS) {
            #pragma unroll
            for (int bb = 0; bb < BT; ++bb)
                #pragma unroll
                for (int pp = 0; pp < 8; ++pp) Sa[bb][pp] += uh[bb][pp];
        } else {
            #pragma unroll
            for (int bb = 0; bb < BT; ++bb) {
                float lg = 0.f;
                #pragma unroll
                for (int pp = 0; pp < 8; ++pp)
                    lg = fmaf(osum[bb][pp], uh[bb][pp], lg);
                lg += __shfl_xor(lg, 1, 64);   // merge p-halves: full 16-p dot
                // softmax over j: butterfly on lane bits 1..5
                float m = lg;
                #pragma unroll
                for (int mk = 2; mk <= 32; mk <<= 1)
                    m = fmaxf(m, __shfl_xor(m, mk, 64));
                float e = __expf(lg - m);
                float se = e;
                #pragma unroll
                for (int mk = 2; mk <= 32; mk <<= 1)
                    se += __shfl_xor(se, mk, 64);
                float c = e * __builtin_amdgcn_rcpf(se);
                #pragma unroll
                for (int pp = 0; pp < 8; ++pp)
                    Sa[bb][pp] = fmaf(c, uh[bb][pp], Sa[bb][pp]);
            }
        }

        if (nn + 1 < BN) {
            store_slice((nn + 1) & 1);  // write next slice (other buffer)
            __syncthreads();
        }
    }

    // ---- flush block-partial S ----
    #pragma unroll
    for (int bb = 0; bb < BT; ++bb) {
        const size_t off = ((size_t)(b0 + wave * BT + bb) * Jj + j) * Pp + hp * 8;
        if (ATOMIC) {
            float* sp = S + off;
            #pragma unroll
            for (int pp = 0; pp < 8; ++pp) atomicAdd(sp + pp, Sa[bb][pp]);
        } else {
            float4* dst = reinterpret_cast<float4*>(S + (size_t)nc * SZ + off);
            dst[0] = make_float4(Sa[bb][0], Sa[bb][1], Sa[bb][2], Sa[bb][3]);
            dst[1] = make_float4(Sa[bb][4], Sa[bb][5], Sa[bb][6], Sa[bb][7]);
        }
    }
}

// Reduce nparts partial S slices, then squash.
// mode 0: OS = v; 1: OS += v; 2: out = v.  One thread per float4 (16384 total).
__global__ void reduce_squash_k(const float* __restrict__ Sp, int nparts,
                                float scale, float* __restrict__ OS,
                                float* __restrict__ out, int mode)
{
    const int t = blockIdx.x * 256 + threadIdx.x;   // 0..16383
    const float4* sp = reinterpret_cast<const float4*>(Sp);
    float4 a = sp[t];
    for (int s = 1; s < nparts; ++s) {
        float4 v = sp[(size_t)s * (SZ / 4) + t];
        a.x += v.x; a.y += v.y; a.z += v.z; a.w += v.w;
    }
    a.x *= scale; a.y *= scale; a.z *= scale; a.w *= scale;
    float s2 = a.x * a.x + a.y * a.y + a.z * a.z + a.w * a.w;
    s2 += __shfl_xor(s2, 1, 64);   // row of 16 p = 4 consecutive threads
    s2 += __shfl_xor(s2, 2, 64);
    const float g = s2 / ((1.f + s2) * sqrtf(s2 + 1e-7f));
    float4 v = make_float4(g * a.x, g * a.y, g * a.z, g * a.w);
    if (mode == 0) {
        reinterpret_cast<float4*>(OS)[t] = v;
    } else if (mode == 1) {
        float4 o = reinterpret_cast<float4*>(OS)[t];
        o.x += v.x; o.y += v.y; o.z += v.z; o.w += v.w;
        reinterpret_cast<float4*>(OS)[t] = o;
    } else {
        reinterpret_cast<float4*>(out)[t] = v;
    }
}

extern "C" void kernel_launch(void* const* d_in, const int* in_sizes, int n_in,
                              void* d_out, int out_size, void* d_ws, size_t ws_size,
                              hipStream_t stream)
{
    const float* x = (const float*)d_in[0];   // [128, 2048, 8]
    const float* W = (const float*)d_in[1];   // [32, 2048, 16, 8]
    float* out = (float*)d_out;               // [128, 32, 16]

    const bool part = ws_size >= (size_t)(NNC + 1) * SZ * sizeof(float); // ~17 MB
    dim3 rg(GRID), rb(256);
    dim3 sg(SZ / 4 / 256), sb(256);           // 64 blocks x 256

    if (part) {
        float* Sp = (float*)d_ws;                 // [64][65536] partials
        float* OS = Sp + (size_t)NNC * SZ;        // running output sum

        route_k<0, 0><<<rg, rb, 0, stream>>>(x, W, nullptr, Sp);
        reduce_squash_k<<<sg, sb, 0, stream>>>(Sp, NNC, 1.f / Jj, OS, out, 0);

        route_k<1, 0><<<rg, rb, 0, stream>>>(x, W, OS, Sp);
        reduce_squash_k<<<sg, sb, 0, stream>>>(Sp, NNC, 1.f, OS, out, 1);

        route_k<1, 0><<<rg, rb, 0, stream>>>(x, W, OS, Sp);
        reduce_squash_k<<<sg, sb, 0, stream>>>(Sp, NNC, 1.f, OS, out, 2);
    } else {
        float* S  = (float*)d_ws;
        float* OS = S + SZ;
        const size_t Sbytes = (size_t)SZ * sizeof(float);

        hipMemsetAsync(S, 0, Sbytes, stream);
        route_k<0, 1><<<rg, rb, 0, stream>>>(x, W, nullptr, S);
        reduce_squash_k<<<sg, sb, 0, stream>>>(S, 1, 1.f / Jj, OS, out, 0);

        hipMemsetAsync(S, 0, Sbytes, stream);
        route_k<1, 1><<<rg, rb, 0, stream>>>(x, W, OS, S);
        reduce_squash_k<<<sg, sb, 0, stream>>>(S, 1, 1.f, OS, out, 1);

        hipMemsetAsync(S, 0, Sbytes, stream);
        route_k<1, 1><<<rg, rb, 0, stream>>>(x, W, OS, S);
        reduce_squash_k<<<sg, sb, 0, stream>>>(S, 1, 1.f, OS, out, 2);
    }
}